// Round 5
// baseline (4755.523 us; speedup 1.0000x reference)
//
#include <hip/hip_runtime.h>
#include <hip/hip_bf16.h>

// SparseBottleneck, output-stationary v4: software-pipelined gather.
// v1-v3 all ran at ~9.5-10G random 64B lines/s = ~9 lines in flight per CU:
// the chunk loop consumed its gather in the same iteration it issued it.
// v4: 2-deep pipeline with alternating register sets (a(c+1) + pk(c+2/3) in
// flight across the whole compute of chunk c), sched_barrier-pinned issue,
// and (tile,half) blocks adjacent in the grid so the half-duplicate gather
// hits XCD L2.

typedef __attribute__((ext_vector_type(8))) short short8;
typedef __attribute__((ext_vector_type(4))) float f32x4;

#define CDIM 128
#define BM   128
#define KTAPS 27
#define LST   65            // lacc stride (odd -> ds_add banks spread)
#define NEG_SLOPE 0.2f

__device__ __forceinline__ unsigned short f2bf(float x) {
    union { float f; unsigned u; } un; un.f = x;
    unsigned r = un.u + 0x7fffu + ((un.u >> 16) & 1u);   // RNE
    return (unsigned short)(r >> 16);
}

__device__ __forceinline__ float lrelu(float x) {
    return x >= 0.f ? x : NEG_SLOPE * x;
}

// swizzled LDS element index for conv2's staging (proven earlier)
__device__ __forceinline__ int swz(int r, int c) {
    return (r << 7) + ((((c >> 3) ^ (r & 15)) << 3));
}

// ---------------------------------------------------------------- converters
__global__ void cvt_feats_kernel(const float* __restrict__ in,
                                 unsigned short* __restrict__ out, int n4) {
    int i = blockIdx.x * blockDim.x + threadIdx.x;
    if (i >= n4) return;
    float4 v = reinterpret_cast<const float4*>(in)[i];
    ushort4 o;
    o.x = f2bf(v.x); o.y = f2bf(v.y); o.z = f2bf(v.z); o.w = f2bf(v.w);
    reinterpret_cast<ushort4*>(out)[i] = o;
}

// W1/W3: [K][Cin][Cout] -> Wt[K][Cout][Cin] bf16. W2 -> W2t[Cout][Cin].
__global__ void cvt_weights_kernel(const float* __restrict__ W1,
                                   const float* __restrict__ W2,
                                   const float* __restrict__ W3,
                                   unsigned short* __restrict__ W1t,
                                   unsigned short* __restrict__ W2t,
                                   unsigned short* __restrict__ W3t) {
    const int KW = KTAPS * 128 * 128;                 // 442368
    int t = blockIdx.x * blockDim.x + threadIdx.x;
    if (t < KW) {
        int k = t >> 14, r = t & 16383, n = r >> 7, kk = r & 127;
        W1t[t] = f2bf(W1[(k << 14) + (kk << 7) + n]);
    } else if (t < 2 * KW) {
        int t2 = t - KW;
        int k = t2 >> 14, r = t2 & 16383, n = r >> 7, kk = r & 127;
        W3t[t2] = f2bf(W3[(k << 14) + (kk << 7) + n]);
    } else if (t < 2 * KW + 16384) {
        int t2 = t - 2 * KW;
        int n = t2 >> 7, kk = t2 & 127;
        W2t[t2] = f2bf(W2[(kk << 7) + n]);
    }
}

// ---------------------------------------------------------------- binning prep
__global__ void hist_kernel(const int* __restrict__ out_map,
                            int* __restrict__ cnt, int M) {
    int m = blockIdx.x * 256 + threadIdx.x;
    if (m >= M) return;
    int k = blockIdx.y;
    int orow = out_map[(size_t)k * M + m];
    atomicAdd(cnt + ((orow >> 7) * KTAPS + k), 1);
}

__global__ void scan_a_kernel(const int* __restrict__ cnt, int* __restrict__ cs,
                              int* __restrict__ partials, int NB) {
    __shared__ int sd[256];
    int tid = threadIdx.x, bin = blockIdx.x * 256 + tid;
    int v = (bin < NB) ? ((cnt[bin] + 15) >> 4) : 0;
    sd[tid] = v; __syncthreads();
    for (int off = 1; off < 256; off <<= 1) {
        int t = (tid >= off) ? sd[tid - off] : 0; __syncthreads();
        sd[tid] += t; __syncthreads();
    }
    if (bin < NB) cs[bin] = sd[tid] - v;      // block-local exclusive
    if (tid == 255) partials[blockIdx.x] = sd[255];
}

__global__ void scan_b_kernel(int* __restrict__ partials, int NBb) {
    __shared__ int sd[256];
    int tid = threadIdx.x;
    int v = (tid < NBb) ? partials[tid] : 0;
    sd[tid] = v; __syncthreads();
    for (int off = 1; off < 256; off <<= 1) {
        int t = (tid >= off) ? sd[tid - off] : 0; __syncthreads();
        sd[tid] += t; __syncthreads();
    }
    partials[tid] = sd[tid] - v;              // exclusive; partials[NBb] = total
}

__global__ void scan_c_kernel(int* __restrict__ cs, const int* __restrict__ partials,
                              int NB, int NBb) {
    int bin = blockIdx.x * 256 + threadIdx.x;
    if (bin < NB) cs[bin] += partials[blockIdx.x];
    if (bin == 0) cs[NB] = partials[NBb];
}

__global__ void fill_kernel(int* __restrict__ p, int n, int v) {
    int i = blockIdx.x * 256 + threadIdx.x;
    if (i < n) p[i] = v;
}

// entry pack: (k<<26) | (in_row<<8) | (out_row & 127)
__global__ void scatter_kernel(const int* __restrict__ in_map,
                               const int* __restrict__ out_map,
                               const int* __restrict__ cs,
                               int* __restrict__ cursor,
                               int* __restrict__ pairs, int M) {
    int m = blockIdx.x * 256 + threadIdx.x;
    if (m >= M) return;
    int k = blockIdx.y;
    size_t e = (size_t)k * M + m;
    int orow = out_map[e], irow = in_map[e];
    int bin = (orow >> 7) * KTAPS + k;
    int pos = atomicAdd(cursor + bin, 1);
    pairs[(size_t)cs[bin] * 16 + pos] = (k << 26) | (irow << 8) | (orow & 127);
}

// ---------------------------------------------------------------- fused sconv
// Grid 2*NT: tile = bid>>1, hhalf = bid&1 (pair adjacent -> L2 gather reuse).
// 512 thr (8 waves), 2 blocks/CU. Each wave: contiguous chunk range, W half
// in 64 VGPRs, 2-deep software pipeline on the A-gather.
#define ISSUE_A(d0, d1, d2, d3, pkv)                                        \
    {   int irow_ = ((pkv) >> 8) & 0x3FFFF;                                 \
        const unsigned short* ar_ = A + ((size_t)irow_ << 7) + quad * 8;    \
        d0 = *reinterpret_cast<const short8*>(ar_);                         \
        d1 = *reinterpret_cast<const short8*>(ar_ + 32);                    \
        d2 = *reinterpret_cast<const short8*>(ar_ + 64);                    \
        d3 = *reinterpret_cast<const short8*>(ar_ + 96); }

#define LOADW(B)                                                            \
    {   const unsigned short* wb_ = Wt + ((size_t)(B) << 14)                \
                  + (((hhalf << 6) + lrow) << 7) + quad * 8;                \
        _Pragma("unroll")                                                   \
        for (int j_ = 0; j_ < 4; ++j_)                                      \
            _Pragma("unroll")                                               \
            for (int s_ = 0; s_ < 4; ++s_)                                  \
                wf[j_][s_] = *reinterpret_cast<const short8*>(wb_ + j_ * 2048 + s_ * 32); }

#define COMPUTE(aa0, aa1, aa2, aa3, pkv)                                    \
    {   int srow_ = (pkv) & 127;                                            \
        int ad0_ = srow_ * LST + quad * 4;                                  \
        _Pragma("unroll")                                                   \
        for (int j_ = 0; j_ < 4; ++j_) {                                    \
            f32x4 acc_ = {0.f, 0.f, 0.f, 0.f};                              \
            acc_ = __builtin_amdgcn_mfma_f32_16x16x32_bf16(wf[j_][0], aa0, acc_, 0, 0, 0); \
            acc_ = __builtin_amdgcn_mfma_f32_16x16x32_bf16(wf[j_][1], aa1, acc_, 0, 0, 0); \
            acc_ = __builtin_amdgcn_mfma_f32_16x16x32_bf16(wf[j_][2], aa2, acc_, 0, 0, 0); \
            acc_ = __builtin_amdgcn_mfma_f32_16x16x32_bf16(wf[j_][3], aa3, acc_, 0, 0, 0); \
            _Pragma("unroll")                                               \
            for (int r_ = 0; r_ < 4; ++r_)                                  \
                __hip_atomic_fetch_add(&lacc[ad0_ + j_ * 16 + r_], acc_[r_],\
                    __ATOMIC_RELAXED, __HIP_MEMORY_SCOPE_WORKGROUP); } }

#define BINCROSS(c)                                                         \
    if ((c) >= nextb) {                                                     \
        do { ++bin; nextb = lcs[bin + 1]; } while ((c) >= nextb);           \
        LOADW(bin);                                                         \
    }

template<int MODE>
__global__ __launch_bounds__(512, 4)
void conv_fused_kernel(const unsigned short* __restrict__ A,    // [N+1,128] bf16, row N = 0
                       const unsigned short* __restrict__ Wt,   // [27][128][128] bf16 [k][n][kk]
                       const int* __restrict__ pairs,
                       const int* __restrict__ cs,              // [NB+1] chunk starts
                       unsigned short* __restrict__ bf_out,     // MODE 0
                       float* __restrict__ f_out,               // MODE 1
                       const float* __restrict__ mask,
                       int N) {
    __shared__ float lacc[128 * LST];                            // 32.5 KB
    __shared__ int lcs[KTAPS + 1];

    const int tid   = threadIdx.x;
    const int tile  = blockIdx.x >> 1;
    const int hhalf = blockIdx.x & 1;
    const int wid   = tid >> 6, lane = tid & 63;
    const int lrow  = lane & 15, quad = lane >> 4;

    for (int i = tid; i < 128 * LST; i += 512) lacc[i] = 0.f;
    if (tid <= KTAPS) lcs[tid] = cs[tile * KTAPS + tid];
    __syncthreads();

    const int lo = lcs[0], hi = lcs[KTAPS];
    const int per = (hi - lo + 7) >> 3;
    int c0 = lo + wid * per;
    int c1 = (c0 + per < hi) ? (c0 + per) : hi;

    if (c0 < c1) {
        int bin = 0;
        while (lcs[bin + 1] <= c0) ++bin;
        int nextb = lcs[bin + 1];
        short8 wf[4][4];                                         // 64 VGPR
        LOADW(bin);

        const int cl = c1 - 1;
        // prologue: pk values for c0, c0+1; pk load for c0+2 pending; A(c0) pending
        int pvc = pairs[(size_t)c0 * 16 + lrow];
        int pvn = pairs[(size_t)((c0 + 1 < cl) ? c0 + 1 : cl) * 16 + lrow];
        int pf  = pairs[(size_t)((c0 + 2 < cl) ? c0 + 2 : cl) * 16 + lrow];
        short8 xa0, xa1, xa2, xa3, ya0, ya1, ya2, ya3;
        ISSUE_A(xa0, xa1, xa2, xa3, pvc);

        int c = c0;
        while (true) {
            // ---- body X: compute chunk c from xa*, issue a(c+1) into ya*
            {
                int pv2 = pf;                                    // wait pk(c+2)
                int i3 = (c + 3 < cl) ? c + 3 : cl;
                pf = pairs[(size_t)i3 * 16 + lrow];              // issue pk(c+3)
                ISSUE_A(ya0, ya1, ya2, ya3, pvn);                // issue a(c+1)
                __builtin_amdgcn_sched_barrier(0);
                BINCROSS(c);
                COMPUTE(xa0, xa1, xa2, xa3, pvc);
                pvc = pvn; pvn = pv2;
            }
            if (++c >= c1) break;
            // ---- body Y: compute chunk c from ya*, issue a(c+1) into xa*
            {
                int pv2 = pf;
                int i3 = (c + 3 < cl) ? c + 3 : cl;
                pf = pairs[(size_t)i3 * 16 + lrow];
                ISSUE_A(xa0, xa1, xa2, xa3, pvn);
                __builtin_amdgcn_sched_barrier(0);
                BINCROSS(c);
                COMPUTE(ya0, ya1, ya2, ya3, pvc);
                pvc = pvn; pvn = pv2;
            }
            if (++c >= c1) break;
        }
    }
    __syncthreads();

    // epilogue: block writes cols [hhalf*64, +64) of its 128 rows, once each
    const int gbase = tile << 7;
    if (MODE == 0) {
        for (int i = tid; i < 128 * 32; i += 512) {              // ushort2 units
            int r = i >> 5, cp = i & 31;
            int g = gbase + r;
            if (g < N) {
                float v0 = lacc[r * LST + cp * 2];
                float v1 = lacc[r * LST + cp * 2 + 1];
                ushort2 o = { f2bf(lrelu(v0)), f2bf(lrelu(v1)) };
                *reinterpret_cast<ushort2*>(bf_out + (size_t)g * CDIM + (hhalf << 6) + cp * 2) = o;
            }
        }
    } else {
        for (int i = tid; i < 128 * 32; i += 512) {              // float2 units
            int r = i >> 5, cp = i & 31;
            int g = gbase + r;
            if (g < N) {
                float mv = mask[g];
                float2 o = { lacc[r * LST + cp * 2] * mv,
                             lacc[r * LST + cp * 2 + 1] * mv };
                *reinterpret_cast<float2*>(f_out + (size_t)g * CDIM + (hhalf << 6) + cp * 2) = o;
            }
        }
    }
}

// ---------------------------------------------------------------- dense conv2
__global__ __launch_bounds__(256, 2)
void conv2_kernel(const unsigned short* __restrict__ c1,      // [N,128] bf16
                  const unsigned short* __restrict__ W2t,     // [128,128] bf16 [n][kk]
                  unsigned short* __restrict__ c2,            // [N,128] bf16
                  int N) {
    const int mbase = blockIdx.x * BM;
    const int tid   = threadIdx.x;

    __shared__ unsigned short lA[BM * CDIM];
    __shared__ unsigned short lW[CDIM * CDIM];

    #pragma unroll
    for (int i = 0; i < 8; ++i) {
        int flat = (i * 256 + tid) * 8;
        int row = flat >> 7, col = flat & 127;
        short8 v = *reinterpret_cast<const short8*>(W2t + flat);
        *reinterpret_cast<short8*>(&lW[swz(row, col)]) = v;
    }

    #pragma unroll
    for (int p = 0; p < 8; ++p) {
        int r = p * 16 + (tid >> 4);
        int c = (tid & 15) * 8;
        int m = mbase + r;
        short8 v = {0, 0, 0, 0, 0, 0, 0, 0};
        if (m < N) v = *reinterpret_cast<const short8*>(c1 + (size_t)m * CDIM + c);
        *reinterpret_cast<short8*>(&lA[swz(r, c)]) = v;
    }
    __syncthreads();

    const int wid  = tid >> 6, lane = tid & 63;
    const int wr   = (wid >> 1) * 64, wc = (wid & 1) * 64;
    const int lrow = lane & 15, quad = lane >> 4;

    f32x4 acc[4][4];
    #pragma unroll
    for (int i = 0; i < 4; ++i)
        #pragma unroll
        for (int j = 0; j < 4; ++j)
            acc[i][j] = {0.f, 0.f, 0.f, 0.f};

    #pragma unroll
    for (int s = 0; s < 4; ++s) {
        const int kf = s * 32 + quad * 8;
        short8 a[4], b[4];
        #pragma unroll
        for (int i = 0; i < 4; ++i)
            a[i] = *reinterpret_cast<const short8*>(&lA[swz(wr + i * 16 + lrow, kf)]);
        #pragma unroll
        for (int j = 0; j < 4; ++j)
            b[j] = *reinterpret_cast<const short8*>(&lW[swz(wc + j * 16 + lrow, kf)]);
        #pragma unroll
        for (int i = 0; i < 4; ++i)
            #pragma unroll
            for (int j = 0; j < 4; ++j)
                acc[i][j] = __builtin_amdgcn_mfma_f32_16x16x32_bf16(a[i], b[j], acc[i][j], 0, 0, 0);
    }

    #pragma unroll
    for (int i = 0; i < 4; ++i) {
        #pragma unroll
        for (int reg = 0; reg < 4; ++reg) {
            int m = mbase + wr + i * 16 + quad * 4 + reg;
            if (m < N) {
                unsigned short* dst = c2 + (size_t)m * CDIM + wc + lrow;
                #pragma unroll
                for (int j = 0; j < 4; ++j)
                    dst[j * 16] = f2bf(lrelu(acc[i][j][reg]));
            }
        }
    }
}

// ---------------------------------------------------------------- launch
extern "C" void kernel_launch(void* const* d_in, const int* in_sizes, int n_in,
                              void* d_out, int out_size, void* d_ws, size_t ws_size,
                              hipStream_t stream) {
    const float* feats   = (const float*)d_in[0];
    const float* W1      = (const float*)d_in[1];
    const float* W2      = (const float*)d_in[2];
    const float* W3      = (const float*)d_in[3];
    const int*   in_map  = (const int*)d_in[4];
    const int*   out_map = (const int*)d_in[5];
    const float* mask    = (const float*)d_in[6];
    float*       out     = (float*)d_out;

    const int K   = KTAPS;
    const int N   = in_sizes[0] / CDIM;           // 200000
    const int M   = in_sizes[4] / K;              // 100000
    const int NT  = (N + 127) >> 7;               // 1563 output tiles
    const int NB  = NT * K;                       // 42201 bins
    const int NBb = (NB + 255) >> 8;              // 165 scan blocks (<=256 req)
    const int CAP = K * M + 16 * NB + 16;         // padded entry capacity

    // workspace layout (512B-aligned sub-buffers)
    char* w = (char*)d_ws;
    size_t o = 0;
    auto alloc = [&](size_t bytes) -> void* {
        void* p = w + o; o = (o + bytes + 511) & ~(size_t)511; return p;
    };
    unsigned short* Abf  = (unsigned short*)alloc((size_t)(N + 1) * CDIM * 2); // feats bf16; reused as c2
    unsigned short* W1t  = (unsigned short*)alloc((size_t)K * CDIM * CDIM * 2);
    unsigned short* W3t  = (unsigned short*)alloc((size_t)K * CDIM * CDIM * 2);
    unsigned short* W2t  = (unsigned short*)alloc((size_t)CDIM * CDIM * 2);
    int* cnt      = (int*)alloc((size_t)NB * 4);
    int* cursor   = (int*)alloc((size_t)NB * 4);
    int* cs       = (int*)alloc((size_t)(NB + 1) * 4);
    int* partials = (int*)alloc(256 * 4);
    int* pairs    = (int*)alloc((size_t)CAP * 4);
    if (o > ws_size) return;   // fail loudly rather than corrupt

    unsigned short* c1bf = (unsigned short*)d_out;   // c1 (bf16, lrelu'd) lives in d_out

    // convert inputs
    const int n4 = N * CDIM / 4;
    cvt_feats_kernel<<<(n4 + 255) / 256, 256, 0, stream>>>(feats, Abf, n4);
    hipMemsetAsync(Abf + (size_t)N * CDIM, 0, CDIM * 2, stream);  // zero row N (dummy target)
    const int wtot = 2 * K * CDIM * CDIM + CDIM * CDIM;
    cvt_weights_kernel<<<(wtot + 255) / 256, 256, 0, stream>>>(W1, W2, W3, W1t, W2t, W3t);

    // binning prep (shared by conv1 & conv3)
    hipMemsetAsync(cnt, 0, (size_t)NB * 4, stream);
    hipMemsetAsync(cursor, 0, (size_t)NB * 4, stream);
    dim3 gmap((M + 255) / 256, K);
    hist_kernel<<<gmap, 256, 0, stream>>>(out_map, cnt, M);
    scan_a_kernel<<<NBb, 256, 0, stream>>>(cnt, cs, partials, NB);
    scan_b_kernel<<<1, 256, 0, stream>>>(partials, NBb);
    scan_c_kernel<<<NBb, 256, 0, stream>>>(cs, partials, NB, NBb);
    const int DUMMY = (N << 8);                   // in_row=N (zero row), scat_row=0, k=0
    fill_kernel<<<(CAP + 255) / 256, 256, 0, stream>>>(pairs, CAP, DUMMY);
    scatter_kernel<<<gmap, 256, 0, stream>>>(in_map, out_map, cs, cursor, pairs, M);

    // conv1: feats -> c1 (bf16, lrelu'd, in d_out)
    conv_fused_kernel<0><<<2 * NT, 512, 0, stream>>>(Abf, W1t, pairs, cs, c1bf, nullptr, nullptr, N);
    // conv2: c1 @ W2 -> c2 (bf16, overwrites Abf; row N stays zero)
    conv2_kernel<<<NT, 256, 0, stream>>>(c1bf, W2t, Abf, N);
    // conv3: c2 -> out (fp32, *mask fused)
    conv_fused_kernel<1><<<2 * NT, 512, 0, stream>>>(Abf, W3t, pairs, cs, nullptr, out, mask, N);
}